// Round 21
// baseline (2795.802 us; speedup 1.0000x reference)
//
#include <hip/hip_runtime.h>
#include <float.h>

__device__ __forceinline__ unsigned short bf16rne(float f) {
  unsigned u = __float_as_uint(f);
  return (unsigned short)((u + 0x7FFFu + ((u >> 16) & 1u)) >> 16);
}

// ---------- CSR build (R15 config: verified 300us) ---------------------------
__global__ void deg_rank_kernel(const int* __restrict__ dst, int* __restrict__ deg,
                                int* __restrict__ rank, int E) {
  int j = blockIdx.x * blockDim.x + threadIdx.x;
  if (j < E) rank[j] = atomicAdd(&deg[dst[j]], 1);
}

__global__ void scan_pass1(const int* __restrict__ deg, int* __restrict__ blocksum, int N) {
  __shared__ int sdata[1024];
  int i = blockIdx.x * 1024 + threadIdx.x;
  sdata[threadIdx.x] = (i < N) ? deg[i] : 0;
  __syncthreads();
  for (int s = 512; s > 0; s >>= 1) {
    if (threadIdx.x < s) sdata[threadIdx.x] += sdata[threadIdx.x + s];
    __syncthreads();
  }
  if (threadIdx.x == 0) blocksum[blockIdx.x] = sdata[0];
}

__global__ void scan_pass2(int* __restrict__ blocksum, int nb) {
  __shared__ int sdata[1024];
  int t = threadIdx.x;
  sdata[t] = (t < nb) ? blocksum[t] : 0;
  __syncthreads();
  if (t == 0) {
    int run = 0;
    for (int i = 0; i < nb; ++i) { int v = sdata[i]; sdata[i] = run; run += v; }
  }
  __syncthreads();
  if (t < nb) blocksum[t] = sdata[t];
}

__global__ void scan_pass3(const int* __restrict__ deg, const int* __restrict__ blocksum,
                           int* __restrict__ rowptr, int N, int E) {
  __shared__ int sdata[1024];
  int i = blockIdx.x * 1024 + threadIdx.x;
  int v = (i < N) ? deg[i] : 0;
  sdata[threadIdx.x] = v;
  __syncthreads();
  for (int off = 1; off < 1024; off <<= 1) {
    int t = (threadIdx.x >= off) ? sdata[threadIdx.x - off] : 0;
    __syncthreads();
    sdata[threadIdx.x] += t;
    __syncthreads();
  }
  if (i < N) rowptr[i] = blocksum[blockIdx.x] + sdata[threadIdx.x] - v;  // exclusive
  if (i == 0) rowptr[N] = E;
}

__global__ void scatter_kernel(const int* __restrict__ dst, const int* __restrict__ rank,
                               const int* __restrict__ rowptr,
                               const int* __restrict__ src, const float* __restrict__ ea,
                               int2* __restrict__ epack, int E) {
  int j = blockIdx.x * blockDim.x + threadIdx.x;
  if (j >= E) return;
  int pos = rowptr[dst[j]] + rank[j];
  epack[pos] = make_int2(src[j], __float_as_int(ea[j]));
}

// ---------- Layer 1 gather ----------------------------------------------------
__global__ void __launch_bounds__(256, 8) gather1_kernel(
    const float* __restrict__ x, const int* __restrict__ rowptr,
    const int2* __restrict__ epack,
    const float* __restrict__ we1, const float* __restrict__ be1,
    float* __restrict__ xin, int N) {
  int i = blockIdx.x * blockDim.x + threadIdx.x;
  if (i >= N) return;
  float we[9], be[9];
#pragma unroll
  for (int f = 0; f < 9; ++f) { we[f] = we1[f]; be[f] = be1[f]; }
  float acc[9];
#pragma unroll
  for (int f = 0; f < 9; ++f) acc[f] = 0.0f;

  int p0 = rowptr[i], p1 = rowptr[i + 1];
  int p = p0;
  for (; p + 1 < p1; p += 2) {
    int2 e0 = epack[p], e1 = epack[p + 1];
    float a0 = __int_as_float(e0.y), a1 = __int_as_float(e1.y);
    float r0[9], r1[9];
#pragma unroll
    for (int f = 0; f < 9; ++f) r0[f] = x[(size_t)e0.x * 9 + f];
#pragma unroll
    for (int f = 0; f < 9; ++f) r1[f] = x[(size_t)e1.x * 9 + f];
#pragma unroll
    for (int f = 0; f < 9; ++f) {
      acc[f] += fmaxf(fmaf(a0, we[f], be[f]) + r0[f], 0.0f);
      acc[f] += fmaxf(fmaf(a1, we[f], be[f]) + r1[f], 0.0f);
    }
  }
  for (; p < p1; ++p) {
    int2 e = epack[p];
    float a = __int_as_float(e.y);
#pragma unroll
    for (int f = 0; f < 9; ++f)
      acc[f] += fmaxf(fmaf(a, we[f], be[f]) + x[(size_t)e.x * 9 + f], 0.0f);
  }
#pragma unroll
  for (int f = 0; f < 9; ++f) xin[(size_t)i * 9 + f] = x[(size_t)i * 9 + f] + acc[f];
}

// ---------- Layer 1 MLP + pack fused: writes ONLY h1b [N][64] bf16 -----------
__global__ void __launch_bounds__(256, 3) node1_mlp(
    const float* __restrict__ xin,
    const float* __restrict__ w11, const float* __restrict__ b11,
    const float* __restrict__ w12, const float* __restrict__ b12,
    unsigned short* __restrict__ h1b, int N) {
  __shared__ float sW1[9 * 64];
  __shared__ float sB1[64];
  __shared__ float sW2t[64 * 64];
  __shared__ float sB2[64];
  __shared__ unsigned short tile[256][66];
  for (int t = threadIdx.x; t < 9 * 64; t += blockDim.x) sW1[t] = w11[t];
  for (int t = threadIdx.x; t < 64 * 64; t += blockDim.x) {
    int o = t >> 6, k = t & 63;
    sW2t[t] = w12[k * 64 + o];
  }
  for (int t = threadIdx.x; t < 64; t += blockDim.x) { sB1[t] = b11[t]; sB2[t] = b12[t]; }
  __syncthreads();
  int i0 = blockIdx.x * 256;
  int i = i0 + threadIdx.x;
  if (i < N) {
    float xv[9];
#pragma unroll
    for (int k = 0; k < 9; ++k) xv[k] = xin[(size_t)i * 9 + k];
    float t1[64];
#pragma unroll
    for (int o = 0; o < 64; ++o) {
      float a = sB1[o];
#pragma unroll
      for (int k = 0; k < 9; ++k) a = fmaf(xv[k], sW1[k * 64 + o], a);
      t1[o] = fmaxf(a, 0.0f);
    }
#pragma unroll
    for (int o = 0; o < 64; ++o) {
      float a = sB2[o];
#pragma unroll
      for (int k = 0; k < 64; k += 4) {
        float4 wv = *(const float4*)(sW2t + o * 64 + k);
        a = fmaf(t1[k], wv.x, a);
        a = fmaf(t1[k + 1], wv.y, a);
        a = fmaf(t1[k + 2], wv.z, a);
        a = fmaf(t1[k + 3], wv.w, a);
      }
      tile[threadIdx.x][o] = bf16rne(fmaxf(a, 0.0f));
    }
  }
  __syncthreads();
#pragma unroll
  for (int it = 0; it < 16; ++it) {
    int idx = it * 256 + threadIdx.x;
    int r = idx >> 4;
    int c = idx & 15;
    if (i0 + r < N) {
      const unsigned short* tp = &tile[r][c * 4];
      uint2 v;
      v.x = (unsigned)tp[0] | ((unsigned)tp[1] << 16);
      v.y = (unsigned)tp[2] | ((unsigned)tp[3] << 16);
      *(uint2*)(h1b + (size_t)(i0 + r) * 64 + c * 4) = v;
    }
  }
}

// ---------- Layer 2 gather: wave-per-node, bf16 rows, self-term folded -------
__device__ __forceinline__ float4 bf4_to_f4(uint2 u) {
  float4 r;
  r.x = __uint_as_float(u.x << 16);
  r.y = __uint_as_float(u.x & 0xFFFF0000u);
  r.z = __uint_as_float(u.y << 16);
  r.w = __uint_as_float(u.y & 0xFFFF0000u);
  return r;
}

__global__ void __launch_bounds__(256, 8) gather2_kernel(
    const unsigned short* __restrict__ h1b, const int* __restrict__ rowptr,
    const int2* __restrict__ epack,
    const float* __restrict__ we2, const float* __restrict__ be2,
    float* __restrict__ agg2, int N) {
  int wid = threadIdx.x >> 6;
  int lane = threadIdx.x & 63;
  int g = lane >> 4;
  int l = lane & 15;
  int i = blockIdx.x * 4 + wid;
  if (i >= N) return;

  float4 we_l = *(const float4*)(we2 + 4 * l);
  float4 be_l = *(const float4*)(be2 + 4 * l);
  float4 acc = make_float4(0.f, 0.f, 0.f, 0.f);

  int p0 = rowptr[i], p1 = rowptr[i + 1];
  int p = p0 + g;
  for (; p + 4 < p1; p += 8) {
    int2 e0 = epack[p], e1 = epack[p + 4];
    float a0 = __int_as_float(e0.y), a1 = __int_as_float(e1.y);
    float4 h0 = bf4_to_f4(*(const uint2*)(h1b + (size_t)e0.x * 64 + 4 * l));
    float4 hv = bf4_to_f4(*(const uint2*)(h1b + (size_t)e1.x * 64 + 4 * l));
    acc.x += fmaxf(fmaf(a0, we_l.x, be_l.x) + h0.x, 0.f);
    acc.y += fmaxf(fmaf(a0, we_l.y, be_l.y) + h0.y, 0.f);
    acc.z += fmaxf(fmaf(a0, we_l.z, be_l.z) + h0.z, 0.f);
    acc.w += fmaxf(fmaf(a0, we_l.w, be_l.w) + h0.w, 0.f);
    acc.x += fmaxf(fmaf(a1, we_l.x, be_l.x) + hv.x, 0.f);
    acc.y += fmaxf(fmaf(a1, we_l.y, be_l.y) + hv.y, 0.f);
    acc.z += fmaxf(fmaf(a1, we_l.z, be_l.z) + hv.z, 0.f);
    acc.w += fmaxf(fmaf(a1, we_l.w, be_l.w) + hv.w, 0.f);
  }
  for (; p < p1; p += 4) {
    int2 e = epack[p];
    float a = __int_as_float(e.y);
    float4 h = bf4_to_f4(*(const uint2*)(h1b + (size_t)e.x * 64 + 4 * l));
    acc.x += fmaxf(fmaf(a, we_l.x, be_l.x) + h.x, 0.f);
    acc.y += fmaxf(fmaf(a, we_l.y, be_l.y) + h.y, 0.f);
    acc.z += fmaxf(fmaf(a, we_l.z, be_l.z) + h.z, 0.f);
    acc.w += fmaxf(fmaf(a, we_l.w, be_l.w) + h.w, 0.f);
  }
#pragma unroll
  for (int off = 16; off <= 32; off <<= 1) {
    acc.x += __shfl_xor(acc.x, off);
    acc.y += __shfl_xor(acc.y, off);
    acc.z += __shfl_xor(acc.z, off);
    acc.w += __shfl_xor(acc.w, off);
  }
  if (g == 0) {
    float4 hs = bf4_to_f4(*(const uint2*)(h1b + (size_t)i * 64 + 4 * l));  // self term
    acc.x += hs.x; acc.y += hs.y; acc.z += hs.z; acc.w += hs.w;
    *(float4*)(agg2 + (size_t)i * 64 + 4 * l) = acc;
  }
}

// ---------- Layer 2 node MLP + readout: 2 nodes/thread -----------------------
// node2 is LDS-pipe-bound (uniform weight broadcast). Register blocking: each
// ds_read_b128 weight read feeds FMAs for TWO nodes -> total LDS instructions
// halve (1563 -> 782 waves x 2560 reads). 128 thr/block covers 256 nodes;
// (128,1) gives VGPR headroom (~280 live) so dual state stays in registers.
__global__ void __launch_bounds__(128, 1) node2_kernel(
    const float* __restrict__ agg2,
    const float* __restrict__ w21, const float* __restrict__ b21,
    const float* __restrict__ w22, const float* __restrict__ b22,
    const float* __restrict__ wr1, const float* __restrict__ br1,
    const float* __restrict__ wr2, const float* __restrict__ br2,
    float* __restrict__ raw, int N) {
  __shared__ float sW1t[64 * 64];   // [o][k]
  __shared__ float sW2t[64 * 64];
  __shared__ float sWr1t[32 * 64];
  __shared__ float sB1[64];
  __shared__ float sB2[64];
  __shared__ float sBr1[32];
  __shared__ float sWr2[32];
  __shared__ float sBr2;
  for (int t = threadIdx.x; t < 64 * 64; t += 128) {
    int o = t >> 6, k = t & 63;
    sW1t[t] = w21[k * 64 + o];
    sW2t[t] = w22[k * 64 + o];
  }
  for (int t = threadIdx.x; t < 32 * 64; t += 128) {
    int o = t >> 6, k = t & 63;
    sWr1t[t] = wr1[k * 32 + o];
  }
  for (int t = threadIdx.x; t < 64; t += 128) { sB1[t] = b21[t]; sB2[t] = b22[t]; }
  for (int t = threadIdx.x; t < 32; t += 128) { sBr1[t] = br1[t]; sWr2[t] = wr2[t]; }
  if (threadIdx.x == 0) sBr2 = br2[0];
  __syncthreads();

  int base = blockIdx.x * 256;
  int i0 = base + threadIdx.x;
  int i1 = i0 + 128;
  bool v0 = (i0 < N), v1 = (i1 < N);
  if (!v0) return;  // i1 >= N implies nothing for this thread's second node only

  float hin0[64], hin1[64];
#pragma unroll
  for (int k = 0; k < 64; k += 4) {
    float4 a = *(const float4*)(agg2 + (size_t)i0 * 64 + k);
    hin0[k] = a.x; hin0[k + 1] = a.y; hin0[k + 2] = a.z; hin0[k + 3] = a.w;
  }
  if (v1) {
#pragma unroll
    for (int k = 0; k < 64; k += 4) {
      float4 a = *(const float4*)(agg2 + (size_t)i1 * 64 + k);
      hin1[k] = a.x; hin1[k + 1] = a.y; hin1[k + 2] = a.z; hin1[k + 3] = a.w;
    }
  } else {
#pragma unroll
    for (int k = 0; k < 64; ++k) hin1[k] = 0.0f;
  }

  float a10[64], a11[64];
#pragma unroll
  for (int o = 0; o < 64; ++o) {
    float c0 = sB1[o], c1 = sB1[o];
#pragma unroll
    for (int k = 0; k < 64; k += 4) {
      float4 wv = *(const float4*)(sW1t + o * 64 + k);
      c0 = fmaf(hin0[k], wv.x, c0);     c1 = fmaf(hin1[k], wv.x, c1);
      c0 = fmaf(hin0[k + 1], wv.y, c0); c1 = fmaf(hin1[k + 1], wv.y, c1);
      c0 = fmaf(hin0[k + 2], wv.z, c0); c1 = fmaf(hin1[k + 2], wv.z, c1);
      c0 = fmaf(hin0[k + 3], wv.w, c0); c1 = fmaf(hin1[k + 3], wv.w, c1);
    }
    a10[o] = fmaxf(c0, 0.0f);
    a11[o] = fmaxf(c1, 0.0f);
  }
  float a20[64], a21[64];
#pragma unroll
  for (int o = 0; o < 64; ++o) {
    float c0 = sB2[o], c1 = sB2[o];
#pragma unroll
    for (int k = 0; k < 64; k += 4) {
      float4 wv = *(const float4*)(sW2t + o * 64 + k);
      c0 = fmaf(a10[k], wv.x, c0);     c1 = fmaf(a11[k], wv.x, c1);
      c0 = fmaf(a10[k + 1], wv.y, c0); c1 = fmaf(a11[k + 1], wv.y, c1);
      c0 = fmaf(a10[k + 2], wv.z, c0); c1 = fmaf(a11[k + 2], wv.z, c1);
      c0 = fmaf(a10[k + 3], wv.w, c0); c1 = fmaf(a11[k + 3], wv.w, c1);
    }
    a20[o] = fmaxf(c0, 0.0f);
    a21[o] = fmaxf(c1, 0.0f);
  }
  float r0[32], r1[32];
#pragma unroll
  for (int o = 0; o < 32; ++o) {
    float c0 = sBr1[o], c1 = sBr1[o];
#pragma unroll
    for (int k = 0; k < 64; k += 4) {
      float4 wv = *(const float4*)(sWr1t + o * 64 + k);
      c0 = fmaf(a20[k], wv.x, c0);     c1 = fmaf(a21[k], wv.x, c1);
      c0 = fmaf(a20[k + 1], wv.y, c0); c1 = fmaf(a21[k + 1], wv.y, c1);
      c0 = fmaf(a20[k + 2], wv.z, c0); c1 = fmaf(a21[k + 2], wv.z, c1);
      c0 = fmaf(a20[k + 3], wv.w, c0); c1 = fmaf(a21[k + 3], wv.w, c1);
    }
    r0[o] = fmaxf(c0, 0.0f);
    r1[o] = fmaxf(c1, 0.0f);
  }
  float acc0 = sBr2, acc1 = sBr2;
#pragma unroll
  for (int k = 0; k < 32; ++k) {
    float wk = sWr2[k];
    acc0 = fmaf(r0[k], wk, acc0);
    acc1 = fmaf(r1[k], wk, acc1);
  }
  raw[i0] = acc0;
  if (v1) raw[i1] = acc1;
}

// ---------- Fused segment softmax: one block per graph (batch is sorted) -----
__device__ __forceinline__ int lowerb(const int* __restrict__ a, int n, int key) {
  int lo = 0, hi = n;
  while (lo < hi) { int mid = (lo + hi) >> 1; if (a[mid] < key) lo = mid + 1; else hi = mid; }
  return lo;
}

__global__ void segsoftmax_kernel(const float* __restrict__ raw, const int* __restrict__ batch,
                                  const float* __restrict__ Btot, float* __restrict__ out, int N) {
  __shared__ float sred[256];
  int g = blockIdx.x;
  int tid = threadIdx.x;
  int start = lowerb(batch, N, g);
  int end = lowerb(batch, N, g + 1);
  if (start >= end) return;

  float m = -FLT_MAX;
  for (int i = start + tid; i < end; i += 256) m = fmaxf(m, raw[i]);
  sred[tid] = m;
  __syncthreads();
  for (int s = 128; s > 0; s >>= 1) {
    if (tid < s) sred[tid] = fmaxf(sred[tid], sred[tid + s]);
    __syncthreads();
  }
  m = sred[0];
  __syncthreads();

  float sum = 0.0f;
  for (int i = start + tid; i < end; i += 256) sum += expf(raw[i] - m);
  sred[tid] = sum;
  __syncthreads();
  for (int s = 128; s > 0; s >>= 1) {
    if (tid < s) sred[tid] += sred[tid + s];
    __syncthreads();
  }
  float scale = Btot[g] / sred[0];

  for (int i = start + tid; i < end; i += 256) out[i] = expf(raw[i] - m) * scale;
}

extern "C" void kernel_launch(void* const* d_in, const int* in_sizes, int n_in,
                              void* d_out, int out_size, void* d_ws, size_t ws_size,
                              hipStream_t stream) {
  const float* x     = (const float*)d_in[0];
  const int* eidx    = (const int*)d_in[1];
  const float* eattr = (const float*)d_in[2];
  const int* batch   = (const int*)d_in[3];
  const float* Btot  = (const float*)d_in[4];
  const float* we1 = (const float*)d_in[5];
  const float* be1 = (const float*)d_in[6];
  const float* w11 = (const float*)d_in[7];
  const float* b11 = (const float*)d_in[8];
  const float* w12 = (const float*)d_in[9];
  const float* b12 = (const float*)d_in[10];
  const float* we2 = (const float*)d_in[11];
  const float* be2 = (const float*)d_in[12];
  const float* w21 = (const float*)d_in[13];
  const float* b21 = (const float*)d_in[14];
  const float* w22 = (const float*)d_in[15];
  const float* b22 = (const float*)d_in[16];
  const float* wr1 = (const float*)d_in[17];
  const float* br1 = (const float*)d_in[18];
  const float* wr2 = (const float*)d_in[19];
  const float* br2 = (const float*)d_in[20];

  const int N  = in_sizes[0] / 9;     // 100000
  const int E  = in_sizes[2];         // 1600000
  const int NG = in_sizes[4];         // 1000
  const int* src = eidx;
  const int* dst = eidx + E;

  const int NB = (N + 1023) / 1024;   // scan blocks (98)

  // workspace layout
  char* w = (char*)d_ws;
  int*   deg    = (int*)w;                 w += (size_t)N * 4;
  int*   rowptr = (int*)w;                 w += (size_t)(N + 1) * 4;
  int*   blocksum = (int*)w;               w += (size_t)1024 * 4;
  int*   rank   = (int*)w;                 w += (size_t)E * 4;
  int2*  epack  = (int2*)w;                w += (size_t)E * 8;
  unsigned short* h1b = (unsigned short*)w; w += (size_t)N * 64 * 2;
  float* agg2   = (float*)w;               w += (size_t)N * 64 * 4;
  float* raw    = (float*)w;               w += (size_t)N * 4;
  float* xin = agg2;  // aliases agg2 (dead until gather2 fully overwrites)

  hipMemsetAsync(deg, 0, (size_t)N * 4, stream);

  dim3 blk(256);
  dim3 egrid((E + 255) / 256);
  dim3 ngrid((N + 255) / 256);

  deg_rank_kernel<<<egrid, blk, 0, stream>>>(dst, deg, rank, E);
  scan_pass1<<<dim3(NB), dim3(1024), 0, stream>>>(deg, blocksum, N);
  scan_pass2<<<dim3(1), dim3(1024), 0, stream>>>(blocksum, NB);
  scan_pass3<<<dim3(NB), dim3(1024), 0, stream>>>(deg, blocksum, rowptr, N, E);
  scatter_kernel<<<egrid, blk, 0, stream>>>(dst, rank, rowptr, src, eattr, epack, E);

  gather1_kernel<<<ngrid, blk, 0, stream>>>(x, rowptr, epack, we1, be1, xin, N);
  node1_mlp<<<ngrid, blk, 0, stream>>>(xin, w11, b11, w12, b12, h1b, N);

  dim3 l2grid((N + 3) / 4);
  gather2_kernel<<<l2grid, blk, 0, stream>>>(h1b, rowptr, epack, we2, be2, agg2, N);
  node2_kernel<<<dim3((N + 255) / 256), dim3(128), 0, stream>>>(
      agg2, w21, b21, w22, b22, wr1, br1, wr2, br2, raw, N);

  segsoftmax_kernel<<<dim3(NG), blk, 0, stream>>>(raw, batch, Btot, (float*)d_out, N);
}

// Round 22
// 299.970 us; speedup vs baseline: 9.3203x; 9.3203x over previous
//
#include <hip/hip_runtime.h>
#include <float.h>

__device__ __forceinline__ unsigned short bf16rne(float f) {
  unsigned u = __float_as_uint(f);
  return (unsigned short)((u + 0x7FFFu + ((u >> 16) & 1u)) >> 16);
}

// ---------- CSR build ---------------------------------------------------------
__global__ void deg_rank_kernel(const int* __restrict__ dst, int* __restrict__ deg,
                                int* __restrict__ rank, int E) {
  int j = blockIdx.x * blockDim.x + threadIdx.x;
  if (j < E) rank[j] = atomicAdd(&deg[dst[j]], 1);
}

__global__ void scan_pass1(const int* __restrict__ deg, int* __restrict__ blocksum, int N) {
  __shared__ int sdata[1024];
  int i = blockIdx.x * 1024 + threadIdx.x;
  sdata[threadIdx.x] = (i < N) ? deg[i] : 0;
  __syncthreads();
  for (int s = 512; s > 0; s >>= 1) {
    if (threadIdx.x < s) sdata[threadIdx.x] += sdata[threadIdx.x + s];
    __syncthreads();
  }
  if (threadIdx.x == 0) blocksum[blockIdx.x] = sdata[0];
}

__global__ void scan_pass2(int* __restrict__ blocksum, int nb) {
  __shared__ int sdata[1024];
  int t = threadIdx.x;
  sdata[t] = (t < nb) ? blocksum[t] : 0;
  __syncthreads();
  if (t == 0) {
    int run = 0;
    for (int i = 0; i < nb; ++i) { int v = sdata[i]; sdata[i] = run; run += v; }
  }
  __syncthreads();
  if (t < nb) blocksum[t] = sdata[t];
}

__global__ void scan_pass3(const int* __restrict__ deg, const int* __restrict__ blocksum,
                           int* __restrict__ rowptr, int N, int E) {
  __shared__ int sdata[1024];
  int i = blockIdx.x * 1024 + threadIdx.x;
  int v = (i < N) ? deg[i] : 0;
  sdata[threadIdx.x] = v;
  __syncthreads();
  for (int off = 1; off < 1024; off <<= 1) {
    int t = (threadIdx.x >= off) ? sdata[threadIdx.x - off] : 0;
    __syncthreads();
    sdata[threadIdx.x] += t;
    __syncthreads();
  }
  if (i < N) rowptr[i] = blocksum[blockIdx.x] + sdata[threadIdx.x] - v;  // exclusive
  if (i == 0) rowptr[N] = E;
}

__global__ void scatter_kernel(const int* __restrict__ dst, const int* __restrict__ rank,
                               const int* __restrict__ rowptr,
                               const int* __restrict__ src, const float* __restrict__ ea,
                               int2* __restrict__ epack, int E) {
  int j = blockIdx.x * blockDim.x + threadIdx.x;
  if (j >= E) return;
  int pos = rowptr[dst[j]] + rank[j];
  epack[pos] = make_int2(src[j], __float_as_int(ea[j]));
}

// ---------- Layer 1 gather ----------------------------------------------------
__global__ void __launch_bounds__(256, 8) gather1_kernel(
    const float* __restrict__ x, const int* __restrict__ rowptr,
    const int2* __restrict__ epack,
    const float* __restrict__ we1, const float* __restrict__ be1,
    float* __restrict__ xin, int N) {
  int i = blockIdx.x * blockDim.x + threadIdx.x;
  if (i >= N) return;
  float we[9], be[9];
#pragma unroll
  for (int f = 0; f < 9; ++f) { we[f] = we1[f]; be[f] = be1[f]; }
  float acc[9];
#pragma unroll
  for (int f = 0; f < 9; ++f) acc[f] = 0.0f;

  int p0 = rowptr[i], p1 = rowptr[i + 1];
  int p = p0;
  for (; p + 1 < p1; p += 2) {
    int2 e0 = epack[p], e1 = epack[p + 1];
    float a0 = __int_as_float(e0.y), a1 = __int_as_float(e1.y);
    float r0[9], r1[9];
#pragma unroll
    for (int f = 0; f < 9; ++f) r0[f] = x[(size_t)e0.x * 9 + f];
#pragma unroll
    for (int f = 0; f < 9; ++f) r1[f] = x[(size_t)e1.x * 9 + f];
#pragma unroll
    for (int f = 0; f < 9; ++f) {
      acc[f] += fmaxf(fmaf(a0, we[f], be[f]) + r0[f], 0.0f);
      acc[f] += fmaxf(fmaf(a1, we[f], be[f]) + r1[f], 0.0f);
    }
  }
  for (; p < p1; ++p) {
    int2 e = epack[p];
    float a = __int_as_float(e.y);
#pragma unroll
    for (int f = 0; f < 9; ++f)
      acc[f] += fmaxf(fmaf(a, we[f], be[f]) + x[(size_t)e.x * 9 + f], 0.0f);
  }
#pragma unroll
  for (int f = 0; f < 9; ++f) xin[(size_t)i * 9 + f] = x[(size_t)i * 9 + f] + acc[f];
}

// ---------- Layer 1 MLP + pack fused: writes ONLY h1b [N][64] bf16 -----------
__global__ void __launch_bounds__(256, 3) node1_mlp(
    const float* __restrict__ xin,
    const float* __restrict__ w11, const float* __restrict__ b11,
    const float* __restrict__ w12, const float* __restrict__ b12,
    unsigned short* __restrict__ h1b, int N) {
  __shared__ float sW1[9 * 64];
  __shared__ float sB1[64];
  __shared__ float sW2t[64 * 64];
  __shared__ float sB2[64];
  __shared__ unsigned short tile[256][66];
  for (int t = threadIdx.x; t < 9 * 64; t += blockDim.x) sW1[t] = w11[t];
  for (int t = threadIdx.x; t < 64 * 64; t += blockDim.x) {
    int o = t >> 6, k = t & 63;
    sW2t[t] = w12[k * 64 + o];
  }
  for (int t = threadIdx.x; t < 64; t += blockDim.x) { sB1[t] = b11[t]; sB2[t] = b12[t]; }
  __syncthreads();
  int i0 = blockIdx.x * 256;
  int i = i0 + threadIdx.x;
  if (i < N) {
    float xv[9];
#pragma unroll
    for (int k = 0; k < 9; ++k) xv[k] = xin[(size_t)i * 9 + k];
    float t1[64];
#pragma unroll
    for (int o = 0; o < 64; ++o) {
      float a = sB1[o];
#pragma unroll
      for (int k = 0; k < 9; ++k) a = fmaf(xv[k], sW1[k * 64 + o], a);
      t1[o] = fmaxf(a, 0.0f);
    }
#pragma unroll
    for (int o = 0; o < 64; ++o) {
      float a = sB2[o];
#pragma unroll
      for (int k = 0; k < 64; k += 4) {
        float4 wv = *(const float4*)(sW2t + o * 64 + k);
        a = fmaf(t1[k], wv.x, a);
        a = fmaf(t1[k + 1], wv.y, a);
        a = fmaf(t1[k + 2], wv.z, a);
        a = fmaf(t1[k + 3], wv.w, a);
      }
      tile[threadIdx.x][o] = bf16rne(fmaxf(a, 0.0f));
    }
  }
  __syncthreads();
#pragma unroll
  for (int it = 0; it < 16; ++it) {
    int idx = it * 256 + threadIdx.x;
    int r = idx >> 4;
    int c = idx & 15;
    if (i0 + r < N) {
      const unsigned short* tp = &tile[r][c * 4];
      uint2 v;
      v.x = (unsigned)tp[0] | ((unsigned)tp[1] << 16);
      v.y = (unsigned)tp[2] | ((unsigned)tp[3] << 16);
      *(uint2*)(h1b + (size_t)(i0 + r) * 64 + c * 4) = v;
    }
  }
}

// ---------- Layer 2 gather: wave-per-node, bf16 rows, self-term folded -------
__device__ __forceinline__ float4 bf4_to_f4(uint2 u) {
  float4 r;
  r.x = __uint_as_float(u.x << 16);
  r.y = __uint_as_float(u.x & 0xFFFF0000u);
  r.z = __uint_as_float(u.y << 16);
  r.w = __uint_as_float(u.y & 0xFFFF0000u);
  return r;
}

__global__ void __launch_bounds__(256, 8) gather2_kernel(
    const unsigned short* __restrict__ h1b, const int* __restrict__ rowptr,
    const int2* __restrict__ epack,
    const float* __restrict__ we2, const float* __restrict__ be2,
    float* __restrict__ agg2, int N) {
  int wid = threadIdx.x >> 6;
  int lane = threadIdx.x & 63;
  int g = lane >> 4;
  int l = lane & 15;
  int i = blockIdx.x * 4 + wid;
  if (i >= N) return;

  float4 we_l = *(const float4*)(we2 + 4 * l);
  float4 be_l = *(const float4*)(be2 + 4 * l);
  float4 acc = make_float4(0.f, 0.f, 0.f, 0.f);

  int p0 = rowptr[i], p1 = rowptr[i + 1];
  int p = p0 + g;
  for (; p + 4 < p1; p += 8) {
    int2 e0 = epack[p], e1 = epack[p + 4];
    float a0 = __int_as_float(e0.y), a1 = __int_as_float(e1.y);
    float4 h0 = bf4_to_f4(*(const uint2*)(h1b + (size_t)e0.x * 64 + 4 * l));
    float4 hv = bf4_to_f4(*(const uint2*)(h1b + (size_t)e1.x * 64 + 4 * l));
    acc.x += fmaxf(fmaf(a0, we_l.x, be_l.x) + h0.x, 0.f);
    acc.y += fmaxf(fmaf(a0, we_l.y, be_l.y) + h0.y, 0.f);
    acc.z += fmaxf(fmaf(a0, we_l.z, be_l.z) + h0.z, 0.f);
    acc.w += fmaxf(fmaf(a0, we_l.w, be_l.w) + h0.w, 0.f);
    acc.x += fmaxf(fmaf(a1, we_l.x, be_l.x) + hv.x, 0.f);
    acc.y += fmaxf(fmaf(a1, we_l.y, be_l.y) + hv.y, 0.f);
    acc.z += fmaxf(fmaf(a1, we_l.z, be_l.z) + hv.z, 0.f);
    acc.w += fmaxf(fmaf(a1, we_l.w, be_l.w) + hv.w, 0.f);
  }
  for (; p < p1; p += 4) {
    int2 e = epack[p];
    float a = __int_as_float(e.y);
    float4 h = bf4_to_f4(*(const uint2*)(h1b + (size_t)e.x * 64 + 4 * l));
    acc.x += fmaxf(fmaf(a, we_l.x, be_l.x) + h.x, 0.f);
    acc.y += fmaxf(fmaf(a, we_l.y, be_l.y) + h.y, 0.f);
    acc.z += fmaxf(fmaf(a, we_l.z, be_l.z) + h.z, 0.f);
    acc.w += fmaxf(fmaf(a, we_l.w, be_l.w) + h.w, 0.f);
  }
#pragma unroll
  for (int off = 16; off <= 32; off <<= 1) {
    acc.x += __shfl_xor(acc.x, off);
    acc.y += __shfl_xor(acc.y, off);
    acc.z += __shfl_xor(acc.z, off);
    acc.w += __shfl_xor(acc.w, off);
  }
  if (g == 0) {
    float4 hs = bf4_to_f4(*(const uint2*)(h1b + (size_t)i * 64 + 4 * l));  // self term
    acc.x += hs.x; acc.y += hs.y; acc.z += hs.z; acc.w += hs.w;
    *(float4*)(agg2 + (size_t)i * 64 + 4 * l) = acc;
  }
}

// ---------- Layer 2 node MLP + readout (R15 verified: 68us, no spill) --------
// fp32 transposed-LDS weights, float4 reads (4 FMA per ds_read_b128), (256,2),
// 512 balanced chunks. Structural floor: uniform weight broadcast through the
// 1-per-CU LDS pipe; bf16 weights (R17) fail accuracy, scalarize (R16) is
// latency-bound, 2-node blocking (R21) spills (448 live floats > 256 VGPR).
__global__ void __launch_bounds__(256, 2) node2_kernel(
    const float* __restrict__ agg2,
    const float* __restrict__ w21, const float* __restrict__ b21,
    const float* __restrict__ w22, const float* __restrict__ b22,
    const float* __restrict__ wr1, const float* __restrict__ br1,
    const float* __restrict__ wr2, const float* __restrict__ br2,
    float* __restrict__ raw, int N, int chunk) {
  __shared__ float sW1t[64 * 64];   // [o][k]
  __shared__ float sW2t[64 * 64];
  __shared__ float sWr1t[32 * 64];
  __shared__ float sB1[64];
  __shared__ float sB2[64];
  __shared__ float sBr1[32];
  __shared__ float sWr2[32];
  __shared__ float sBr2;
  for (int t = threadIdx.x; t < 64 * 64; t += blockDim.x) {
    int o = t >> 6, k = t & 63;
    sW1t[t] = w21[k * 64 + o];
    sW2t[t] = w22[k * 64 + o];
  }
  for (int t = threadIdx.x; t < 32 * 64; t += blockDim.x) {
    int o = t >> 6, k = t & 63;
    sWr1t[t] = wr1[k * 32 + o];
  }
  for (int t = threadIdx.x; t < 64; t += blockDim.x) { sB1[t] = b21[t]; sB2[t] = b22[t]; }
  for (int t = threadIdx.x; t < 32; t += blockDim.x) { sBr1[t] = br1[t]; sWr2[t] = wr2[t]; }
  if (threadIdx.x == 0) sBr2 = br2[0];
  __syncthreads();
  int i = blockIdx.x * chunk + threadIdx.x;
  if ((int)threadIdx.x >= chunk || i >= N) return;
  float hin[64];
#pragma unroll
  for (int k = 0; k < 64; k += 4) {
    float4 v = *(const float4*)(agg2 + (size_t)i * 64 + k);
    hin[k] = v.x; hin[k + 1] = v.y; hin[k + 2] = v.z; hin[k + 3] = v.w;
  }
  float a1[64];
#pragma unroll
  for (int o = 0; o < 64; ++o) {
    float acc = sB1[o];
#pragma unroll
    for (int k = 0; k < 64; k += 4) {
      float4 wv = *(const float4*)(sW1t + o * 64 + k);
      acc = fmaf(hin[k], wv.x, acc);
      acc = fmaf(hin[k + 1], wv.y, acc);
      acc = fmaf(hin[k + 2], wv.z, acc);
      acc = fmaf(hin[k + 3], wv.w, acc);
    }
    a1[o] = fmaxf(acc, 0.0f);
  }
  float a2[64];
#pragma unroll
  for (int o = 0; o < 64; ++o) {
    float acc = sB2[o];
#pragma unroll
    for (int k = 0; k < 64; k += 4) {
      float4 wv = *(const float4*)(sW2t + o * 64 + k);
      acc = fmaf(a1[k], wv.x, acc);
      acc = fmaf(a1[k + 1], wv.y, acc);
      acc = fmaf(a1[k + 2], wv.z, acc);
      acc = fmaf(a1[k + 3], wv.w, acc);
    }
    a2[o] = fmaxf(acc, 0.0f);
  }
  float r[32];
#pragma unroll
  for (int o = 0; o < 32; ++o) {
    float acc = sBr1[o];
#pragma unroll
    for (int k = 0; k < 64; k += 4) {
      float4 wv = *(const float4*)(sWr1t + o * 64 + k);
      acc = fmaf(a2[k], wv.x, acc);
      acc = fmaf(a2[k + 1], wv.y, acc);
      acc = fmaf(a2[k + 2], wv.z, acc);
      acc = fmaf(a2[k + 3], wv.w, acc);
    }
    r[o] = fmaxf(acc, 0.0f);
  }
  float acc = sBr2;
#pragma unroll
  for (int k = 0; k < 32; ++k) acc = fmaf(r[k], sWr2[k], acc);
  raw[i] = acc;
}

// ---------- Fused segment softmax: one block per graph (batch is sorted) -----
__device__ __forceinline__ int lowerb(const int* __restrict__ a, int n, int key) {
  int lo = 0, hi = n;
  while (lo < hi) { int mid = (lo + hi) >> 1; if (a[mid] < key) lo = mid + 1; else hi = mid; }
  return lo;
}

__global__ void segsoftmax_kernel(const float* __restrict__ raw, const int* __restrict__ batch,
                                  const float* __restrict__ Btot, float* __restrict__ out, int N) {
  __shared__ float sred[256];
  int g = blockIdx.x;
  int tid = threadIdx.x;
  int start = lowerb(batch, N, g);
  int end = lowerb(batch, N, g + 1);
  if (start >= end) return;

  float m = -FLT_MAX;
  for (int i = start + tid; i < end; i += 256) m = fmaxf(m, raw[i]);
  sred[tid] = m;
  __syncthreads();
  for (int s = 128; s > 0; s >>= 1) {
    if (tid < s) sred[tid] = fmaxf(sred[tid], sred[tid + s]);
    __syncthreads();
  }
  m = sred[0];
  __syncthreads();

  float sum = 0.0f;
  for (int i = start + tid; i < end; i += 256) sum += expf(raw[i] - m);
  sred[tid] = sum;
  __syncthreads();
  for (int s = 128; s > 0; s >>= 1) {
    if (tid < s) sred[tid] += sred[tid + s];
    __syncthreads();
  }
  float scale = Btot[g] / sred[0];

  for (int i = start + tid; i < end; i += 256) out[i] = expf(raw[i] - m) * scale;
}

extern "C" void kernel_launch(void* const* d_in, const int* in_sizes, int n_in,
                              void* d_out, int out_size, void* d_ws, size_t ws_size,
                              hipStream_t stream) {
  const float* x     = (const float*)d_in[0];
  const int* eidx    = (const int*)d_in[1];
  const float* eattr = (const float*)d_in[2];
  const int* batch   = (const int*)d_in[3];
  const float* Btot  = (const float*)d_in[4];
  const float* we1 = (const float*)d_in[5];
  const float* be1 = (const float*)d_in[6];
  const float* w11 = (const float*)d_in[7];
  const float* b11 = (const float*)d_in[8];
  const float* w12 = (const float*)d_in[9];
  const float* b12 = (const float*)d_in[10];
  const float* we2 = (const float*)d_in[11];
  const float* be2 = (const float*)d_in[12];
  const float* w21 = (const float*)d_in[13];
  const float* b21 = (const float*)d_in[14];
  const float* w22 = (const float*)d_in[15];
  const float* b22 = (const float*)d_in[16];
  const float* wr1 = (const float*)d_in[17];
  const float* br1 = (const float*)d_in[18];
  const float* wr2 = (const float*)d_in[19];
  const float* br2 = (const float*)d_in[20];

  const int N  = in_sizes[0] / 9;     // 100000
  const int E  = in_sizes[2];         // 1600000
  const int NG = in_sizes[4];         // 1000
  const int* src = eidx;
  const int* dst = eidx + E;

  const int NB = (N + 1023) / 1024;   // scan blocks (98)

  // workspace layout
  char* w = (char*)d_ws;
  int*   deg    = (int*)w;                 w += (size_t)N * 4;
  int*   rowptr = (int*)w;                 w += (size_t)(N + 1) * 4;
  int*   blocksum = (int*)w;               w += (size_t)1024 * 4;
  int*   rank   = (int*)w;                 w += (size_t)E * 4;
  int2*  epack  = (int2*)w;                w += (size_t)E * 8;
  unsigned short* h1b = (unsigned short*)w; w += (size_t)N * 64 * 2;
  float* agg2   = (float*)w;               w += (size_t)N * 64 * 4;
  float* raw    = (float*)w;               w += (size_t)N * 4;
  float* xin = agg2;  // aliases agg2 (dead until gather2 fully overwrites)

  hipMemsetAsync(deg, 0, (size_t)N * 4, stream);

  dim3 blk(256);
  dim3 egrid((E + 255) / 256);
  dim3 ngrid((N + 255) / 256);

  deg_rank_kernel<<<egrid, blk, 0, stream>>>(dst, deg, rank, E);
  scan_pass1<<<dim3(NB), dim3(1024), 0, stream>>>(deg, blocksum, N);
  scan_pass2<<<dim3(1), dim3(1024), 0, stream>>>(blocksum, NB);
  scan_pass3<<<dim3(NB), dim3(1024), 0, stream>>>(deg, blocksum, rowptr, N, E);
  scatter_kernel<<<egrid, blk, 0, stream>>>(dst, rank, rowptr, src, eattr, epack, E);

  gather1_kernel<<<ngrid, blk, 0, stream>>>(x, rowptr, epack, we1, be1, xin, N);
  node1_mlp<<<ngrid, blk, 0, stream>>>(xin, w11, b11, w12, b12, h1b, N);

  dim3 l2grid((N + 3) / 4);
  gather2_kernel<<<l2grid, blk, 0, stream>>>(h1b, rowptr, epack, we2, be2, agg2, N);
  const int N2B = 512;                       // 2 blocks per CU, balanced chunks
  const int chunk = (N + N2B - 1) / N2B;     // 196
  node2_kernel<<<dim3(N2B), blk, 0, stream>>>(agg2, w21, b21, w22, b22,
                                              wr1, br1, wr2, br2, raw, N, chunk);

  segsoftmax_kernel<<<dim3(NG), blk, 0, stream>>>(raw, batch, Btot, (float*)d_out, N);
}